// Round 8
// baseline (306.651 us; speedup 1.0000x reference)
//
#include <hip/hip_runtime.h>

// MultiBoxLoss_four_corners — B=64, P=8732, C=81, NEG_POS_RATIO=3
// Outputs: (loss_l/N, loss_c/N, loss_four_corners/N) -> d_out[0..2] (f32)
//
// R10: every structure R0-R9 reads at 2.4-2.7 TB/s (~80% of copy's read
// side). Last distinguishing lever vs a pure stream: segments per wave-instr.
// k_ce now uses 16 LANES PER ROW: each dwordx4 wave-instr = 4 rows x 16
// consecutive chunks = 4x256B segments (2 segments/row vs 6 with 4-lane/row).
// Two clamped loads/lane/row; out-of-row components masked by bi<81 (overlap
// bytes are L1 hits, HBM traffic unchanged). Depth-2 register pipeline,
// in-register tgt extract, 4-deep shfl reduce. k_sl1/k_batch/k_final as R9.

#define NB 64
#define NP 8732
#define NC 81
constexpr int BP = NB * NP;              // 558848
constexpr int PBLK = (NP + 255) / 256;   // 35 blocks per batch (tail 28)
constexpr unsigned MAXCH = (unsigned)((size_t)BP * NC / 4 - 1);  // 11316671

__device__ inline float sl1(float d) {
    d = fabsf(d);
    return d < 1.0f ? 0.5f * d * d : d - 0.5f;
}

// ws layout (floats): ce[BP] | partS[NB*PBLK*4] | partC[NB*PBLK*2]
//                     | loss_c_b[64] | npos_b[64](int) | lsum_b[64] | fsum_b[64]

// ---------- smooth-L1 + npos: 7 coalesced streams, one prior/thread ----------
__global__ __launch_bounds__(256) void k_sl1(
    const float* __restrict__ loc_data, const float* __restrict__ fc_data,
    const float* __restrict__ loc_t,    const float* __restrict__ fc_t,
    const int* __restrict__ conf_t,     float* __restrict__ partS)
{
    const int b  = blockIdx.y;
    const int bx = blockIdx.x;
    const int t  = threadIdx.x;
    const int p  = (bx << 8) + t;

    __shared__ float red[4][3];
    float l_sum = 0.0f, f_sum = 0.0f;
    int np = 0;

    if (p < NP) {
        const size_t g = (size_t)b * NP + p;
        const int tgt = conf_t[g];
        const float posf = (tgt > 0) ? 1.0f : 0.0f;
        np = (tgt > 0) ? 1 : 0;
        float4 a4  = ((const float4*)loc_data)[g];
        float4 a4t = ((const float4*)loc_t)[g];
        float4 c0  = ((const float4*)fc_data)[2 * g];
        float4 c1  = ((const float4*)fc_data)[2 * g + 1];
        float4 d0  = ((const float4*)fc_t)[2 * g];
        float4 d1  = ((const float4*)fc_t)[2 * g + 1];
        l_sum = (sl1(a4.x - a4t.x) + sl1(a4.y - a4t.y) +
                 sl1(a4.z - a4t.z) + sl1(a4.w - a4t.w)) * posf;
        f_sum = (sl1(c0.x - d0.x) + sl1(c0.y - d0.y) + sl1(c0.z - d0.z) + sl1(c0.w - d0.w) +
                 sl1(c1.x - d1.x) + sl1(c1.y - d1.y) + sl1(c1.z - d1.z) + sl1(c1.w - d1.w)) * posf;
    }

    const int wave = t >> 6, lane = t & 63;
    float vnp = (float)np;
    #pragma unroll
    for (int o = 32; o; o >>= 1) {
        l_sum += __shfl_xor(l_sum, o, 64);
        f_sum += __shfl_xor(f_sum, o, 64);
        vnp   += __shfl_xor(vnp, o, 64);
    }
    if (lane == 0) { red[wave][0] = l_sum; red[wave][1] = f_sum; red[wave][2] = vnp; }
    __syncthreads();
    if (t == 0) {
        float rl = 0, rf = 0, rc = 0;
        #pragma unroll
        for (int w = 0; w < 4; ++w) { rl += red[w][0]; rf += red[w][1]; rc += red[w][2]; }
        float* ps = partS + ((size_t)b * PBLK + bx) * 4;
        ps[0] = rl; ps[1] = rf; ps[2] = rc;
    }
}

// ---------- CE: 16 lanes/row, 2 contiguous 256B-segment loads, depth-2 ----------
// Row r: floats [fb, fb+81), 21 chunks c0..c0+20. Lane sub in [0,16):
//   load0 = chunk c0+sub        (16 consecutive chunks, always in-row-span)
//   load1 = chunk c0+16+sub     (covers c0+16..c0+20; rest auto-masked by bi)
// Wave-instr = 4 rows (grp = lane>>4) x 16 consecutive chunks = 4x256B segments.

#define CE_ISSUE(BUF, S)                                                 \
    if ((S) < 16) {                                                      \
        const int pl = (wave << 6) + ((S) << 2) + grp;                   \
        const int p  = p0 + pl;                                          \
        const int pe = min(p, NP - 1);                                   \
        const unsigned fb = ((unsigned)b * NP + (unsigned)pe) * (unsigned)NC; \
        const unsigned c0 = fb >> 2;                                     \
        unsigned ch1 = c0 + 16u + (unsigned)sub;                         \
        ch1 = ch1 > MAXCH ? MAXCH : ch1;                                 \
        BUF##_v0 = conf4[c0 + (unsigned)sub];                            \
        BUF##_v1 = conf4[ch1];                                           \
        BUF##_p  = p;                                                    \
        BUF##_al = (int)(fb & 3u);                                       \
    }

#define CE_COMPUTE(BUF, S)                                               \
    if ((S) < 16) {                                                      \
        const int pl  = (wave << 6) + ((S) << 2) + grp;                  \
        const int tgt = tgt_s[pl];                                       \
        const int al  = BUF##_al;                                        \
        float e = 0.0f, tv = 0.0f;                                       \
        {                                                                \
            const float4 v = BUF##_v0;                                   \
            const int bi = 4 * sub - al;                                 \
            e  += ((unsigned)(bi + 0) < 81u) ? __expf(v.x) : 0.0f;       \
            e  += ((unsigned)(bi + 1) < 81u) ? __expf(v.y) : 0.0f;       \
            e  += ((unsigned)(bi + 2) < 81u) ? __expf(v.z) : 0.0f;       \
            e  += ((unsigned)(bi + 3) < 81u) ? __expf(v.w) : 0.0f;       \
            tv += (bi + 0 == tgt) ? v.x : 0.0f;                          \
            tv += (bi + 1 == tgt) ? v.y : 0.0f;                          \
            tv += (bi + 2 == tgt) ? v.z : 0.0f;                          \
            tv += (bi + 3 == tgt) ? v.w : 0.0f;                          \
        }                                                                \
        {                                                                \
            const float4 v = BUF##_v1;                                   \
            const int bi = 4 * (sub + 16) - al;                          \
            e  += ((unsigned)(bi + 0) < 81u) ? __expf(v.x) : 0.0f;       \
            e  += ((unsigned)(bi + 1) < 81u) ? __expf(v.y) : 0.0f;       \
            e  += ((unsigned)(bi + 2) < 81u) ? __expf(v.z) : 0.0f;       \
            e  += ((unsigned)(bi + 3) < 81u) ? __expf(v.w) : 0.0f;       \
            tv += (bi + 0 == tgt) ? v.x : 0.0f;                          \
            tv += (bi + 1 == tgt) ? v.y : 0.0f;                          \
            tv += (bi + 2 == tgt) ? v.z : 0.0f;                          \
            tv += (bi + 3 == tgt) ? v.w : 0.0f;                          \
        }                                                                \
        e  += __shfl_xor(e, 1, 64);  e  += __shfl_xor(e, 2, 64);         \
        e  += __shfl_xor(e, 4, 64);  e  += __shfl_xor(e, 8, 64);         \
        tv += __shfl_xor(tv, 1, 64); tv += __shfl_xor(tv, 2, 64);        \
        tv += __shfl_xor(tv, 4, 64); tv += __shfl_xor(tv, 8, 64);        \
        if (sub == 0 && BUF##_p < NP) {                                  \
            const unsigned g = (unsigned)b * NP + (unsigned)BUF##_p;     \
            const float cev = __logf(e) - tv;                            \
            ce[g] = cev;                                                 \
            if (tgt > 0) sp += cev; else sn += cev;                      \
        }                                                                \
    }

__global__ __launch_bounds__(256) void k_ce(
    const float* __restrict__ conf_data, const int* __restrict__ conf_t,
    float* __restrict__ ce, float* __restrict__ partC)
{
    const int b  = blockIdx.y;
    const int bx = blockIdx.x;
    const int t  = threadIdx.x;
    const int p0 = bx << 8;

    __shared__ int   tgt_s[256];
    __shared__ float red[4][2];

    {
        const int p = p0 + t;
        tgt_s[t] = (p < NP) ? conf_t[(size_t)b * NP + p] : 0;
    }
    __syncthreads();

    const int wave = t >> 6, lane = t & 63;
    const int grp = lane >> 4, sub = lane & 15;
    const float4* conf4 = (const float4*)conf_data;
    float sp = 0.0f, sn = 0.0f;

    float4 A_v0, A_v1, B_v0, B_v1;
    int A_p, A_al, B_p, B_al;

    CE_ISSUE(A, 0);
    CE_ISSUE(B, 1);
    #pragma unroll
    for (int s = 0; s < 16; s += 2) {
        CE_COMPUTE(A, s);
        CE_ISSUE(A, s + 2);
        CE_COMPUTE(B, s + 1);
        CE_ISSUE(B, s + 3);
    }

    // block reduce sp, sn -> private slot
    #pragma unroll
    for (int o = 32; o; o >>= 1) {
        sp += __shfl_xor(sp, o, 64);
        sn += __shfl_xor(sn, o, 64);
    }
    if (lane == 0) { red[wave][0] = sp; red[wave][1] = sn; }
    __syncthreads();
    if (t == 0) {
        float rp = 0, rn = 0;
        #pragma unroll
        for (int w = 0; w < 4; ++w) { rp += red[w][0]; rn += red[w][1]; }
        float* pc = partC + ((size_t)b * PBLK + bx) * 2;
        pc[0] = rp; pc[1] = rn;
    }
}

// One block per batch: reduce 35 partial slots, then mining path.
__global__ __launch_bounds__(256) void k_batch(
    const float* __restrict__ ce, const int* __restrict__ conf_t,
    const float* __restrict__ partS, const float* __restrict__ partC,
    float* __restrict__ loss_c_b, int* __restrict__ npos_b,
    float* __restrict__ lsum_b, float* __restrict__ fsum_b)
{
    const int b = blockIdx.x;
    const int t = threadIdx.x;
    __shared__ float hdr[3];                  // spos, sneg, nposf

    if (t < 64) {                             // wave 0 reduces 35 slots
        float v0 = 0, v1 = 0, v2 = 0, v3 = 0, v4 = 0;
        if (t < PBLK) {
            const float* ps = partS + ((size_t)b * PBLK + t) * 4;
            v0 = ps[0]; v1 = ps[1]; v4 = ps[2];
            const float* pc = partC + ((size_t)b * PBLK + t) * 2;
            v2 = pc[0]; v3 = pc[1];
        }
        #pragma unroll
        for (int o = 32; o; o >>= 1) {
            v0 += __shfl_xor(v0, o, 64);
            v1 += __shfl_xor(v1, o, 64);
            v2 += __shfl_xor(v2, o, 64);
            v3 += __shfl_xor(v3, o, 64);
            v4 += __shfl_xor(v4, o, 64);
        }
        if (t == 0) {
            lsum_b[b] = v0; fsum_b[b] = v1;
            npos_b[b] = (int)v4;
            hdr[0] = v2; hdr[1] = v3; hdr[2] = v4;
        }
    }
    __syncthreads();

    const float spos = hdr[0], sneg = hdr[1];
    const int npos    = (int)hdr[2];
    const int nneg    = NP - npos;
    const int num_neg = min(3 * npos, NP - 1);

    if (num_neg >= nneg) {              // all negatives selected (this dataset)
        if (t == 0) loss_c_b[b] = spos + sneg;
        return;
    }
    if (num_neg <= 0) {
        if (t == 0) loss_c_b[b] = spos;
        return;
    }

    // general path: stage negative CE into LDS (positives -> -1), top-K sum
    __shared__ float ce_s[NP];
    __shared__ float sredf[4];
    __shared__ int   sredi[4];
    const float* crow = ce + (size_t)b * NP;
    const int*   trow = conf_t + (size_t)b * NP;
    for (int p = t; p < NP; p += 256)
        ce_s[p] = (trow[p] > 0) ? -1.0f : crow[p];
    __syncthreads();

    const int wave = t >> 6, lane = t & 63;
    const int K = num_neg;
    unsigned lo = 0u, hi = 0x7f800000u;
    while (lo < hi) {
        unsigned mid = lo + ((hi - lo) >> 1);
        float v = __uint_as_float(mid);
        int c_t = 0;
        for (int p = t; p < NP; p += 256) c_t += (ce_s[p] > v) ? 1 : 0;
        #pragma unroll
        for (int o = 32; o; o >>= 1) c_t += __shfl_xor(c_t, o, 64);
        __syncthreads();
        if (lane == 0) sredi[wave] = c_t;
        __syncthreads();
        int cnt = sredi[0] + sredi[1] + sredi[2] + sredi[3];
        if (cnt < K) hi = mid; else lo = mid + 1;
    }
    float v = __uint_as_float(lo);       // K-th largest negative CE
    int c_t = 0; float s_t = 0.0f;
    for (int p = t; p < NP; p += 256) {
        float x = ce_s[p];
        if (x > v) { c_t++; s_t += x; }
    }
    #pragma unroll
    for (int o = 32; o; o >>= 1) {
        c_t += __shfl_xor(c_t, o, 64);
        s_t += __shfl_xor(s_t, o, 64);
    }
    __syncthreads();
    if (lane == 0) { sredi[wave] = c_t; sredf[wave] = s_t; }
    __syncthreads();
    if (t == 0) {
        int   cnt = sredi[0] + sredi[1] + sredi[2] + sredi[3];
        float sgt = sredf[0] + sredf[1] + sredf[2] + sredf[3];
        loss_c_b[b] = spos + sgt + (float)(K - cnt) * v;
    }
}

__global__ void k_final(const float* __restrict__ loss_c_b,
                        const int* __restrict__ npos_b,
                        const float* __restrict__ lsum_b,
                        const float* __restrict__ fsum_b,
                        float* __restrict__ out)
{
    const int t = threadIdx.x;           // 64 threads
    float lc = loss_c_b[t];
    float ls = lsum_b[t];
    float fs = fsum_b[t];
    int   np = npos_b[t];
    #pragma unroll
    for (int o = 32; o; o >>= 1) {
        lc += __shfl_xor(lc, o, 64);
        ls += __shfl_xor(ls, o, 64);
        fs += __shfl_xor(fs, o, 64);
        np += __shfl_xor(np, o, 64);
    }
    if (t == 0) {
        float N = (float)np;
        out[0] = ls / N;
        out[1] = lc / N;
        out[2] = fs / N;
    }
}

extern "C" void kernel_launch(void* const* d_in, const int* in_sizes, int n_in,
                              void* d_out, int out_size, void* d_ws, size_t ws_size,
                              hipStream_t stream)
{
    const float* loc_data  = (const float*)d_in[0];
    const float* conf_data = (const float*)d_in[1];
    const float* fc_data   = (const float*)d_in[2];
    const float* loc_t     = (const float*)d_in[3];
    const float* fc_t      = (const float*)d_in[4];
    const int*   conf_t    = (const int*)d_in[5];
    float* out = (float*)d_out;

    float* ce       = (float*)d_ws;
    float* partS    = ce + BP;                   // [NB*PBLK*4] = 8960
    float* partC    = partS + NB * PBLK * 4;     // [NB*PBLK*2] = 4480
    float* loss_c_b = partC + NB * PBLK * 2;     // [64]
    int*   npos_b   = (int*)(loss_c_b + 64);     // [64]
    float* lsum_b   = (float*)(npos_b + 64);     // [64]
    float* fsum_b   = lsum_b + 64;               // [64]

    hipLaunchKernelGGL(k_sl1,  dim3(PBLK, NB), dim3(256), 0, stream,
                       loc_data, fc_data, loc_t, fc_t, conf_t, partS);
    hipLaunchKernelGGL(k_ce,   dim3(PBLK, NB), dim3(256), 0, stream,
                       conf_data, conf_t, ce, partC);
    hipLaunchKernelGGL(k_batch, dim3(NB), dim3(256), 0, stream,
                       ce, conf_t, partS, partC, loss_c_b, npos_b, lsum_b, fsum_b);
    hipLaunchKernelGGL(k_final, dim3(1), dim3(64), 0, stream,
                       loss_c_b, npos_b, lsum_b, fsum_b, out);
}